// Round 1
// baseline (386.496 us; speedup 1.0000x reference)
//
#include <hip/hip_runtime.h>

#define BATCH   2
#define SEQLEN  2048
#define DMODEL  1024
#define DINNER  2048
#define NHEADS  64
#define HEADDIM 32
#define DSTATE  16
#define CONVDIM 2080
#define DINPROJ 4192
#define NPAD    4224
#define CHUNK   256
#define NCHUNK  8
#define BL      (BATCH*SEQLEN)   // 4096
#define XWIDTH  2144             // CONVDIM + NHEADS

typedef float  f4    __attribute__((ext_vector_type(4)));
typedef short  s16x8 __attribute__((ext_vector_type(8)));
typedef __bf16 bf16x8 __attribute__((ext_vector_type(8)));
typedef float  f32x4v __attribute__((ext_vector_type(4)));

__device__ __forceinline__ unsigned short f2bf(float f){
  unsigned int u = __float_as_uint(f);
  u += 0x7FFFu + ((u >> 16) & 1u);
  return (unsigned short)(u >> 16);
}

// ---------------- casts ----------------
__global__ void cast_f32_bf16(const float* __restrict__ in, unsigned short* __restrict__ out, int n){
  int i = blockIdx.x * 256 + threadIdx.x;
  if (i < n) out[i] = f2bf(in[i]);
}

__global__ void cast_win_pad(const float* __restrict__ in, unsigned short* __restrict__ out){
  int i = blockIdx.x * 256 + threadIdx.x;
  if (i >= NPAD * DMODEL) return;
  int r = i >> 10;  // /1024
  out[i] = (r < DINPROJ) ? f2bf(in[i]) : (unsigned short)0;
}

// ---------------- bf16 MFMA GEMM: C[M,N] = A[M,K] * B[N,K]^T ----------------
// MODE 0: in_proj epilogue: col<2048 -> z (ld 2048); 2048<=col<4192 -> ws xbcdt (ld 2144)
// MODE 1: plain store to C0 with ld N
template<int MODE>
__global__ __launch_bounds__(256) void gemm_bf16(
    const unsigned short* __restrict__ A,
    const unsigned short* __restrict__ B,
    int K, float* __restrict__ C0, float* __restrict__ C1, int N)
{
  __shared__ unsigned short As[128][40];  // +8 pad: 80B rows -> conflict-free b128
  __shared__ unsigned short Bs[128][40];
  const int tid  = threadIdx.x;
  const int bm   = blockIdx.y, bn = blockIdx.x;
  const int wave = tid >> 6, lane = tid & 63;
  const int wm   = (wave >> 1) * 64, wn = (wave & 1) * 64;
  const int lrow = lane & 15, lko = (lane >> 4) * 8;
  const int r0   = tid >> 2;          // 0..63
  const int c0   = (tid & 3) * 8;     // bf16 offset in K-step
  const unsigned short* Ag = A + (size_t)(bm * 128 + r0) * K + c0;
  const unsigned short* Bg = B + (size_t)(bn * 128 + r0) * K + c0;

  f32x4v acc[4][4];
  #pragma unroll
  for (int i = 0; i < 4; ++i)
    #pragma unroll
    for (int j = 0; j < 4; ++j)
      acc[i][j] = (f32x4v){0.f,0.f,0.f,0.f};

  for (int k0 = 0; k0 < K; k0 += 32) {
    s16x8 a0 = *(const s16x8*)(Ag);
    s16x8 a1 = *(const s16x8*)(Ag + (size_t)64 * K);
    s16x8 b0 = *(const s16x8*)(Bg);
    s16x8 b1 = *(const s16x8*)(Bg + (size_t)64 * K);
    *(s16x8*)&As[r0][c0]      = a0;
    *(s16x8*)&As[64 + r0][c0] = a1;
    *(s16x8*)&Bs[r0][c0]      = b0;
    *(s16x8*)&Bs[64 + r0][c0] = b1;
    __syncthreads();
    bf16x8 af[4], bfr[4];
    #pragma unroll
    for (int i = 0; i < 4; ++i) {
      af[i]  = *(const bf16x8*)&As[wm + i * 16 + lrow][lko];
      bfr[i] = *(const bf16x8*)&Bs[wn + i * 16 + lrow][lko];
    }
    #pragma unroll
    for (int mi = 0; mi < 4; ++mi)
      #pragma unroll
      for (int ni = 0; ni < 4; ++ni)
        acc[mi][ni] = __builtin_amdgcn_mfma_f32_16x16x32_bf16(af[mi], bfr[ni], acc[mi][ni], 0, 0, 0);
    __syncthreads();
    Ag += 32; Bg += 32;
  }

  const int orow0 = bm * 128 + wm;
  const int ocol0 = bn * 128 + wn;
  #pragma unroll
  for (int mi = 0; mi < 4; ++mi)
    #pragma unroll
    for (int ni = 0; ni < 4; ++ni) {
      int col  = ocol0 + ni * 16 + (lane & 15);
      int rowb = orow0 + mi * 16 + (lane >> 4) * 4;
      #pragma unroll
      for (int r = 0; r < 4; ++r) {
        int row = rowb + r;
        float v = acc[mi][ni][r];
        if (MODE == 0) {
          if (col < DINNER)        C0[(size_t)row * DINNER + col] = v;
          else if (col < DINPROJ)  C1[(size_t)row * XWIDTH + (col - DINNER)] = v;
        } else {
          C0[(size_t)row * N + col] = v;
        }
      }
    }
}

// ---------------- conv1d (depthwise causal, silu) + dt softplus ----------------
__global__ void conv_dt_kernel(const float* __restrict__ xbcdt,
                               const float* __restrict__ conv_w, const float* __restrict__ conv_b,
                               const float* __restrict__ dt_bias,
                               float* __restrict__ xconv, float* __restrict__ dtout)
{
  int idx = blockIdx.x * 256 + threadIdx.x;
  if (idx >= BL * XWIDTH) return;
  int ch = idx % XWIDTH;
  int bl = idx / XWIDTH;
  int l  = bl & (SEQLEN - 1);
  if (ch < CONVDIM) {
    float acc = conv_b[ch];
    #pragma unroll
    for (int j = 0; j < 4; ++j) {
      int ls = l - 3 + j;
      float x = (ls >= 0) ? xbcdt[(size_t)(bl - 3 + j) * XWIDTH + ch] : 0.f;
      acc += conv_w[ch * 4 + j] * x;
    }
    float s = acc / (1.f + __expf(-acc));
    xconv[(size_t)bl * CONVDIM + ch] = s;
  } else {
    int h = ch - CONVDIM;
    float x = xbcdt[(size_t)bl * XWIDTH + ch] + dt_bias[h];
    float dtv = (x > 20.f) ? x : log1pf(__expf(x));
    dtout[bl * NHEADS + h] = dtv;
  }
}

// ---------------- SSD phase A: Acum scan + chunk states ----------------
__global__ __launch_bounds__(256) void ssd_phaseA(
    const float* __restrict__ xconv, const float* __restrict__ dt,
    const float* __restrict__ A_log,
    float* __restrict__ acum, float* __restrict__ decay, float* __restrict__ states)
{
  int bc = blockIdx.x, h = blockIdx.y;
  int b = bc >> 3;
  int t = threadIdx.x;
  __shared__ float sAc[256], sCoef[256], sDt[256];
  __shared__ float sB[256][16];
  __shared__ float sX[256][32];
  int rowbase = b * SEQLEN + (bc & 7) * CHUNK;
  float dtv = dt[(rowbase + t) * NHEADS + h];
  float Av  = -__expf(A_log[h]);
  sAc[t] = dtv * Av; sDt[t] = dtv;
  for (int i = t; i < 256 * 16; i += 256) { int l = i >> 4, n = i & 15; sB[l][n] = xconv[(size_t)(rowbase + l) * CONVDIM + DINNER + n]; }
  for (int i = t; i < 256 * 32; i += 256) { int l = i >> 5, p = i & 31; sX[l][p] = xconv[(size_t)(rowbase + l) * CONVDIM + h * 32 + p]; }
  __syncthreads();
  for (int off = 1; off < 256; off <<= 1) {
    float add = (t >= off) ? sAc[t - off] : 0.f;
    __syncthreads();
    sAc[t] += add;
    __syncthreads();
  }
  int bch = bc * 64 + h;
  acum[(size_t)bch * 256 + t] = sAc[t];
  float last = sAc[255];
  if (t == 0) decay[bch] = __expf(last);
  sCoef[t] = sDt[t] * __expf(last - sAc[t]);
  __syncthreads();
  #pragma unroll
  for (int o = 0; o < 2; ++o) {
    int oi = t + o * 256;
    int p = oi >> 4, n = oi & 15;
    float acc = 0.f;
    for (int l = 0; l < 256; ++l) acc += sCoef[l] * sB[l][n] * sX[l][p];
    states[(size_t)bch * 512 + oi] = acc;
  }
}

// ---------------- SSD phase B: sequential chunk scan ----------------
__global__ void ssd_phaseB(const float* __restrict__ states, const float* __restrict__ decay,
                           float* __restrict__ prev)
{
  int bh = blockIdx.x;           // b*64+h, 128 blocks
  int b = bh >> 6, h = bh & 63;
  int t = threadIdx.x;           // 512
  float carry = 0.f;
  for (int c = 0; c < NCHUNK; ++c) {
    int bch = (b * 8 + c) * 64 + h;
    size_t base = (size_t)bch * 512 + t;
    prev[base] = carry;
    carry = decay[bch] * carry + states[base];
  }
}

// ---------------- SSD phase C: Y = (CB∘L)xdt + exp(Acum)·C·prev + D·x ----------------
__global__ __launch_bounds__(128) void ssd_phaseC(
    const float* __restrict__ xconv, const float* __restrict__ dt,
    const float* __restrict__ acum, const float* __restrict__ prev,
    const float* __restrict__ Dvec, float* __restrict__ y)
{
  int bc = blockIdx.x, h = blockIdx.y;
  int b = bc >> 3;
  int t = threadIdx.x;           // 0..127, rows t and t+128
  __shared__ float sAc[256];
  __shared__ float sB[256][16];
  __shared__ float sX[256][32];  // xdt
  __shared__ float sPrev[512];
  int rowbase = b * SEQLEN + (bc & 7) * CHUNK;
  int bch = bc * 64 + h;
  for (int i = t; i < 256; i += 128) sAc[i] = acum[(size_t)bch * 256 + i];
  for (int i = t; i < 512; i += 128) sPrev[i] = prev[(size_t)bch * 512 + i];
  for (int i = t; i < 256 * 16; i += 128) { int l = i >> 4, n = i & 15; sB[l][n] = xconv[(size_t)(rowbase + l) * CONVDIM + DINNER + n]; }
  for (int i = t; i < 256 * 32; i += 128) { int l = i >> 5, p = i & 31; sX[l][p] = xconv[(size_t)(rowbase + l) * CONVDIM + h * 32 + p] * dt[(rowbase + l) * NHEADS + h]; }
  __syncthreads();

  const int r0 = t, r1 = t + 128;
  float cr0[16], cr1[16];
  #pragma unroll
  for (int n = 0; n < 16; ++n) {
    cr0[n] = xconv[(size_t)(rowbase + r0) * CONVDIM + DINNER + DSTATE + n];
    cr1[n] = xconv[(size_t)(rowbase + r1) * CONVDIM + DINNER + DSTATE + n];
  }
  float a0 = sAc[r0], a1 = sAc[r1];
  float e0 = __expf(a0), e1 = __expf(a1);
  float Dh = Dvec[h];
  float acc0[32], acc1[32];
  #pragma unroll
  for (int p = 0; p < 32; ++p) {
    float s0 = 0.f, s1 = 0.f;
    #pragma unroll
    for (int n = 0; n < 16; ++n) { s0 += cr0[n] * sPrev[p * 16 + n]; s1 += cr1[n] * sPrev[p * 16 + n]; }
    acc0[p] = e0 * s0 + Dh * xconv[(size_t)(rowbase + r0) * CONVDIM + h * 32 + p];
    acc1[p] = e1 * s1 + Dh * xconv[(size_t)(rowbase + r1) * CONVDIM + h * 32 + p];
  }

  for (int s = 0; s <= r1; ++s) {
    const f4* b4 = (const f4*)sB[s];
    float d0 = 0.f, d1 = 0.f;
    #pragma unroll
    for (int q = 0; q < 4; ++q) {
      f4 bv = b4[q];
      d0 += cr0[4*q+0]*bv[0] + cr0[4*q+1]*bv[1] + cr0[4*q+2]*bv[2] + cr0[4*q+3]*bv[3];
      d1 += cr1[4*q+0]*bv[0] + cr1[4*q+1]*bv[1] + cr1[4*q+2]*bv[2] + cr1[4*q+3]*bv[3];
    }
    float as = sAc[s];
    float c0 = (s <= r0) ? d0 * __expf(fminf(a0 - as, 0.f)) : 0.f;
    float c1 = d1 * __expf(fminf(a1 - as, 0.f));   // s<=r1 by loop bound
    const f4* x4 = (const f4*)sX[s];
    #pragma unroll
    for (int q = 0; q < 8; ++q) {
      f4 xv = x4[q];
      acc0[4*q+0] += c0 * xv[0]; acc0[4*q+1] += c0 * xv[1]; acc0[4*q+2] += c0 * xv[2]; acc0[4*q+3] += c0 * xv[3];
      acc1[4*q+0] += c1 * xv[0]; acc1[4*q+1] += c1 * xv[1]; acc1[4*q+2] += c1 * xv[2]; acc1[4*q+3] += c1 * xv[3];
    }
  }

  float* yp0 = y + (size_t)(rowbase + r0) * DINNER + h * 32;
  float* yp1 = y + (size_t)(rowbase + r1) * DINNER + h * 32;
  #pragma unroll
  for (int q = 0; q < 8; ++q) {
    ((f4*)yp0)[q] = (f4){acc0[4*q+0], acc0[4*q+1], acc0[4*q+2], acc0[4*q+3]};
    ((f4*)yp1)[q] = (f4){acc1[4*q+0], acc1[4*q+1], acc1[4*q+2], acc1[4*q+3]};
  }
}

// ---------------- gate (silu(z)) + RMSNorm -> bf16 ----------------
__global__ __launch_bounds__(256) void gate_norm(const float* __restrict__ y,
    const float* __restrict__ z, const float* __restrict__ norm_w,
    unsigned short* __restrict__ ynbf)
{
  int row = blockIdx.x, t = threadIdx.x;
  const float* yr = y + (size_t)row * DINNER;
  const float* zr = z + (size_t)row * DINNER;
  float vals[8];
  float ss = 0.f;
  #pragma unroll
  for (int i = 0; i < 8; ++i) {
    int ci = t + i * 256;
    float zv = zr[ci];
    float g = zv / (1.f + __expf(-zv));
    float v = yr[ci] * g;
    vals[i] = v; ss += v * v;
  }
  #pragma unroll
  for (int o = 1; o < 64; o <<= 1) ss += __shfl_xor(ss, o);
  __shared__ float sred[4];
  if ((t & 63) == 0) sred[t >> 6] = ss;
  __syncthreads();
  float tot = sred[0] + sred[1] + sred[2] + sred[3];
  float scale = rsqrtf(tot * (1.f / DINNER) + 1e-5f);
  #pragma unroll
  for (int i = 0; i < 8; ++i) {
    int ci = t + i * 256;
    ynbf[(size_t)row * DINNER + ci] = f2bf(vals[i] * scale * norm_w[ci]);
  }
}

// ---------------- launch ----------------
extern "C" void kernel_launch(void* const* d_in, const int* in_sizes, int n_in,
                              void* d_out, int out_size, void* d_ws, size_t ws_size,
                              hipStream_t stream)
{
  const float* u       = (const float*)d_in[0];
  const float* W_in    = (const float*)d_in[1];
  const float* conv_w  = (const float*)d_in[2];
  const float* conv_b  = (const float*)d_in[3];
  const float* dt_bias = (const float*)d_in[4];
  const float* A_log   = (const float*)d_in[5];
  const float* Dv      = (const float*)d_in[6];
  const float* norm_w  = (const float*)d_in[7];
  const float* W_out   = (const float*)d_in[8];

  float* out  = (float*)d_out;
  float* zout = out + (size_t)BL * DMODEL;   // z region: 4096x2048

  char* ws = (char*)d_ws;
  size_t off = 0;
  auto alloc = [&](size_t bytes){ size_t o = off; off += (bytes + 255) & ~(size_t)255; return o; };
  size_t o_ubf    = alloc((size_t)BL * DMODEL * 2);        // also reused for W_out bf16
  size_t o_wbf    = alloc((size_t)NPAD * DMODEL * 2);
  size_t o_xbcdt  = alloc((size_t)BL * XWIDTH * 4);        // reused as y after conv
  size_t o_xconv  = alloc((size_t)BL * CONVDIM * 4);
  size_t o_dt     = alloc((size_t)BL * NHEADS * 4);
  size_t o_acum   = alloc((size_t)1024 * 256 * 4);
  size_t o_decay  = alloc((size_t)1024 * 4);
  size_t o_states = alloc((size_t)1024 * 512 * 4);
  size_t o_prev   = alloc((size_t)1024 * 512 * 4);
  size_t o_ynbf   = alloc((size_t)BL * DINNER * 2);

  unsigned short* ubf    = (unsigned short*)(ws + o_ubf);
  unsigned short* wbf    = (unsigned short*)(ws + o_wbf);
  float*          xbcdt  = (float*)(ws + o_xbcdt);
  float*          xconv  = (float*)(ws + o_xconv);
  float*          dtws   = (float*)(ws + o_dt);
  float*          acum   = (float*)(ws + o_acum);
  float*          decay  = (float*)(ws + o_decay);
  float*          states = (float*)(ws + o_states);
  float*          prevb  = (float*)(ws + o_prev);
  unsigned short* ynbf   = (unsigned short*)(ws + o_ynbf);
  unsigned short* woutbf = ubf;          // reuse (u bf16 dead after gemm_in)
  float*          ywork  = xbcdt;        // reuse (xbcdt dead after conv)

  cast_f32_bf16<<<(BL * DMODEL) / 256, 256, 0, stream>>>(u, ubf, BL * DMODEL);
  cast_win_pad<<<(NPAD * DMODEL) / 256, 256, 0, stream>>>(W_in, wbf);

  gemm_bf16<0><<<dim3(NPAD / 128, BL / 128), 256, 0, stream>>>(ubf, wbf, DMODEL, zout, xbcdt, 0);

  conv_dt_kernel<<<(BL * XWIDTH) / 256, 256, 0, stream>>>(xbcdt, conv_w, conv_b, dt_bias, xconv, dtws);

  ssd_phaseA<<<dim3(16, 64), 256, 0, stream>>>(xconv, dtws, A_log, acum, decay, states);
  ssd_phaseB<<<128, 512, 0, stream>>>(states, decay, prevb);
  ssd_phaseC<<<dim3(16, 64), 128, 0, stream>>>(xconv, dtws, acum, prevb, Dv, ywork);

  gate_norm<<<BL, 256, 0, stream>>>(ywork, zout, norm_w, ynbf);

  cast_f32_bf16<<<(DMODEL * DINNER) / 256, 256, 0, stream>>>(W_out, woutbf, DMODEL * DINNER);

  gemm_bf16<1><<<dim3(DMODEL / 128, BL / 128), 256, 0, stream>>>(ynbf, woutbf, DINNER, out, nullptr, DMODEL);
}

// Round 3
// 256.388 us; speedup vs baseline: 1.5075x; 1.5075x over previous
//
#include <hip/hip_runtime.h>

#define BATCH   2
#define SEQLEN  2048
#define DMODEL  1024
#define DINNER  2048
#define NHEADS  64
#define HEADDIM 32
#define DSTATE  16
#define CONVDIM 2080
#define DINPROJ 4192
#define NPAD    4224
#define CHUNK   256
#define NCHUNK  8
#define BL      (BATCH*SEQLEN)   // 4096
#define XWIDTH  2144             // CONVDIM + NHEADS

typedef float  f4    __attribute__((ext_vector_type(4)));
typedef short  s16x8 __attribute__((ext_vector_type(8)));
typedef __bf16 bf16x8 __attribute__((ext_vector_type(8)));
typedef float  f32x4v __attribute__((ext_vector_type(4)));

#define MFMA16(a,b,c) __builtin_amdgcn_mfma_f32_16x16x32_bf16((a),(b),(c),0,0,0)

__device__ __forceinline__ unsigned short f2bf(float f){
  unsigned int u = __float_as_uint(f);
  u += 0x7FFFu + ((u >> 16) & 1u);
  return (unsigned short)(u >> 16);
}

__device__ __forceinline__ void gload_lds16(const void* g, void* l){
  __builtin_amdgcn_global_load_lds((const __attribute__((address_space(1))) unsigned int*)g,
                                   (__attribute__((address_space(3))) unsigned int*)l,
                                   16, 0, 0);
}

// load 8 consecutive f32 -> bf16x8 fragment; if !valid, return zeros.
__device__ __forceinline__ bf16x8 f32x8_to_frag(const float* src, bool valid){
  bf16x8 r;
  if (valid) {
    f4 a = *(const f4*)src;
    f4 c = *(const f4*)(src + 4);
    r[0]=(__bf16)a[0]; r[1]=(__bf16)a[1]; r[2]=(__bf16)a[2]; r[3]=(__bf16)a[3];
    r[4]=(__bf16)c[0]; r[5]=(__bf16)c[1]; r[6]=(__bf16)c[2]; r[7]=(__bf16)c[3];
  } else {
    r[0]=(__bf16)0.f; r[1]=(__bf16)0.f; r[2]=(__bf16)0.f; r[3]=(__bf16)0.f;
    r[4]=(__bf16)0.f; r[5]=(__bf16)0.f; r[6]=(__bf16)0.f; r[7]=(__bf16)0.f;
  }
  return r;
}

// ---------------- casts ----------------
__global__ void cast_f32_bf16(const float* __restrict__ in, unsigned short* __restrict__ out, int n){
  int i = blockIdx.x * 256 + threadIdx.x;
  if (i < n) out[i] = f2bf(in[i]);
}

__global__ void cast_win_pad(const float* __restrict__ in, unsigned short* __restrict__ out){
  int i = blockIdx.x * 256 + threadIdx.x;
  if (i >= NPAD * DMODEL) return;
  int r = i >> 10;  // /1024
  out[i] = (r < DINPROJ) ? f2bf(in[i]) : (unsigned short)0;
}

// ---------------- bf16 MFMA GEMM: C[M,N] = A[M,K] * B[N,K]^T ----------------
// m97-style: global_load_lds width-16 staging, linear LDS, 2-barrier K-loop.
// MODE 0: in_proj epilogue split (z / xbcdt); MODE 1: plain store ld N.
template<int MODE>
__global__ __launch_bounds__(256) void gemm_bf16(
    const unsigned short* __restrict__ A,
    const unsigned short* __restrict__ B,
    int K, float* __restrict__ C0, float* __restrict__ C1, int N)
{
  __shared__ unsigned short As[128][32];
  __shared__ unsigned short Bs[128][32];
  const int tid  = threadIdx.x;
  const int bm   = blockIdx.y, bn = blockIdx.x;
  const int wave = tid >> 6, lane = tid & 63;
  const int wm   = (wave >> 1) * 64, wn = (wave & 1) * 64;
  const int lrow = lane & 15, lko = (lane >> 4) * 8;

  // staging: wave w issues 2 loads per matrix; lane -> row (lane>>2), 16B chunk (lane&3)
  const int srow = wave * 16 + (lane >> 2);
  const int scol = (lane & 3) * 8;
  const unsigned short* Ag = A + (size_t)(bm * 128 + srow) * K + scol;
  const unsigned short* Bg = B + (size_t)(bn * 128 + srow) * K + scol;
  unsigned short* As0 = &As[wave * 16][0];
  unsigned short* As1 = &As[64 + wave * 16][0];
  unsigned short* Bs0 = &Bs[wave * 16][0];
  unsigned short* Bs1 = &Bs[64 + wave * 16][0];

  f32x4v acc[4][4];
  #pragma unroll
  for (int i = 0; i < 4; ++i)
    #pragma unroll
    for (int j = 0; j < 4; ++j)
      acc[i][j] = (f32x4v){0.f,0.f,0.f,0.f};

  for (int k0 = 0; k0 < K; k0 += 32) {
    gload_lds16(Ag, As0);
    gload_lds16(Ag + (size_t)64 * K, As1);
    gload_lds16(Bg, Bs0);
    gload_lds16(Bg + (size_t)64 * K, Bs1);
    __syncthreads();
    bf16x8 af[4], bfr[4];
    #pragma unroll
    for (int i = 0; i < 4; ++i) {
      af[i]  = *(const bf16x8*)&As[wm + i * 16 + lrow][lko];
      bfr[i] = *(const bf16x8*)&Bs[wn + i * 16 + lrow][lko];
    }
    #pragma unroll
    for (int mi = 0; mi < 4; ++mi)
      #pragma unroll
      for (int ni = 0; ni < 4; ++ni)
        acc[mi][ni] = MFMA16(af[mi], bfr[ni], acc[mi][ni]);
    __syncthreads();
    Ag += 32; Bg += 32;
  }

  const int orow0 = bm * 128 + wm;
  const int ocol0 = bn * 128 + wn;
  #pragma unroll
  for (int mi = 0; mi < 4; ++mi)
    #pragma unroll
    for (int ni = 0; ni < 4; ++ni) {
      int col  = ocol0 + ni * 16 + (lane & 15);
      int rowb = orow0 + mi * 16 + (lane >> 4) * 4;
      #pragma unroll
      for (int r = 0; r < 4; ++r) {
        int row = rowb + r;
        float v = acc[mi][ni][r];
        if (MODE == 0) {
          if (col < DINNER)        C0[(size_t)row * DINNER + col] = v;
          else if (col < DINPROJ)  C1[(size_t)row * XWIDTH + (col - DINNER)] = v;
        } else {
          C0[(size_t)row * N + col] = v;
        }
      }
    }
}

// ---------------- conv1d (depthwise causal, silu) + dt softplus ----------------
__global__ void conv_dt_kernel(const float* __restrict__ xbcdt,
                               const float* __restrict__ conv_w, const float* __restrict__ conv_b,
                               const float* __restrict__ dt_bias,
                               float* __restrict__ xconv, float* __restrict__ dtout)
{
  int idx = blockIdx.x * 256 + threadIdx.x;
  if (idx >= BL * XWIDTH) return;
  int ch = idx % XWIDTH;
  int bl = idx / XWIDTH;
  int l  = bl & (SEQLEN - 1);
  if (ch < CONVDIM) {
    float acc = conv_b[ch];
    #pragma unroll
    for (int j = 0; j < 4; ++j) {
      int ls = l - 3 + j;
      float x = (ls >= 0) ? xbcdt[(size_t)(bl - 3 + j) * XWIDTH + ch] : 0.f;
      acc += conv_w[ch * 4 + j] * x;
    }
    float s = acc / (1.f + __expf(-acc));
    xconv[(size_t)bl * CONVDIM + ch] = s;
  } else {
    int h = ch - CONVDIM;
    float x = xbcdt[(size_t)bl * XWIDTH + ch] + dt_bias[h];
    float dtv = (x > 20.f) ? x : log1pf(__expf(x));
    dtout[bl * NHEADS + h] = dtv;
  }
}

// ---------------- SSD phase A: Acum scan + chunk states ----------------
__global__ __launch_bounds__(256) void ssd_phaseA(
    const float* __restrict__ xconv, const float* __restrict__ dt,
    const float* __restrict__ A_log,
    float* __restrict__ acum, float* __restrict__ decay, float* __restrict__ states)
{
  int bc = blockIdx.x, h = blockIdx.y;
  int b = bc >> 3;
  int t = threadIdx.x;
  __shared__ float sAc[256], sCoef[256], sDt[256];
  __shared__ float sB[256][16];
  __shared__ float sX[256][32];
  int rowbase = b * SEQLEN + (bc & 7) * CHUNK;
  float dtv = dt[(rowbase + t) * NHEADS + h];
  float Av  = -__expf(A_log[h]);
  sAc[t] = dtv * Av; sDt[t] = dtv;
  for (int i = t; i < 256 * 16; i += 256) { int l = i >> 4, n = i & 15; sB[l][n] = xconv[(size_t)(rowbase + l) * CONVDIM + DINNER + n]; }
  for (int i = t; i < 256 * 32; i += 256) { int l = i >> 5, p = i & 31; sX[l][p] = xconv[(size_t)(rowbase + l) * CONVDIM + h * 32 + p]; }
  __syncthreads();
  for (int off = 1; off < 256; off <<= 1) {
    float add = (t >= off) ? sAc[t - off] : 0.f;
    __syncthreads();
    sAc[t] += add;
    __syncthreads();
  }
  int bch = bc * 64 + h;
  acum[(size_t)bch * 256 + t] = sAc[t];
  float last = sAc[255];
  if (t == 0) decay[bch] = __expf(last);
  sCoef[t] = sDt[t] * __expf(last - sAc[t]);
  __syncthreads();
  #pragma unroll
  for (int o = 0; o < 2; ++o) {
    int oi = t + o * 256;
    int p = oi >> 4, n = oi & 15;
    float acc = 0.f;
    for (int l = 0; l < 256; ++l) acc += sCoef[l] * sB[l][n] * sX[l][p];
    states[(size_t)bch * 512 + oi] = acc;
  }
}

// ---------------- SSD phase B: sequential chunk scan ----------------
__global__ void ssd_phaseB(const float* __restrict__ states, const float* __restrict__ decay,
                           float* __restrict__ prev)
{
  int bh = blockIdx.x;           // b*64+h, 128 blocks
  int b = bh >> 6, h = bh & 63;
  int t = threadIdx.x;           // 512
  float carry = 0.f;
  for (int c = 0; c < NCHUNK; ++c) {
    int bch = (b * 8 + c) * 64 + h;
    size_t base = (size_t)bch * 512 + t;
    prev[base] = carry;
    carry = decay[bch] * carry + states[base];
  }
}

// ---------------- SSD phase C (MFMA): Y = (CB^T ∘ L)·xdt + e^{acum}·C·prev^T + D·x ----
__global__ __launch_bounds__(256, 2) void ssd_phaseC_mfma(
    const float* __restrict__ xconv, const float* __restrict__ dt,
    const float* __restrict__ acum, const float* __restrict__ prev,
    const float* __restrict__ Dvec, float* __restrict__ y)
{
  const int bc = blockIdx.x, h = blockIdx.y;
  const int b = bc >> 3;
  const int rowbase = b * SEQLEN + (bc & 7) * CHUNK;
  const int bch = bc * 64 + h;
  const int tid = threadIdx.x, wave = tid >> 6, lane = tid & 63;
  const int l16 = lane & 15, khalf = lane >> 4;

  __shared__ float sAcum[256];
  __shared__ __bf16 sXT[32][264];          // [p][s] = x[s][p]*dt[s]
  __shared__ __bf16 sP[4][2][16][40];      // per-wave double-buffered P slab

  if (tid < 256) sAcum[tid] = acum[(size_t)bch * 256 + tid];
  {
    int l  = tid >> 3;
    int p0 = (tid & 7) * 4;
    #pragma unroll
    for (int pass = 0; pass < 8; ++pass) {
      int ls = l + pass * 32;
      const float* xr = xconv + (size_t)(rowbase + ls) * CONVDIM + h * 32 + p0;
      f4 v = *(const f4*)xr;
      float dtl = dt[(rowbase + ls) * NHEADS + h];
      #pragma unroll
      for (int j = 0; j < 4; ++j) sXT[p0 + j][ls] = (__bf16)(v[j] * dtl);
    }
  }

  // register fragments (upper-K halves zeroed so B-pad can't leak)
  const bool kv = (khalf < 2);
  bf16x8 bfr[16], cfr[4], pvf[2];
  #pragma unroll
  for (int i = 0; i < 16; ++i)
    bfr[i] = f32x8_to_frag(xconv + (size_t)(rowbase + i * 16 + l16) * CONVDIM + DINNER + khalf * 8, kv);
  #pragma unroll
  for (int t = 0; t < 4; ++t)
    cfr[t] = f32x8_to_frag(xconv + (size_t)(rowbase + (wave + 4 * t) * 16 + l16) * CONVDIM + DINNER + DSTATE + khalf * 8, kv);
  #pragma unroll
  for (int pt = 0; pt < 2; ++pt)
    pvf[pt] = f32x8_to_frag(prev + (size_t)bch * 512 + (pt * 16 + l16) * 16 + khalf * 8, kv);
  __syncthreads();

  const float Dh = Dvec[h];
  #pragma unroll
  for (int t = 0; t < 4; ++t) {
    const int LT = wave + 4 * t;
    const int lbase = LT * 16;
    float al[4], el[4];
    #pragma unroll
    for (int r = 0; r < 4; ++r) { al[r] = sAcum[lbase + khalf * 4 + r]; el[r] = __expf(al[r]); }
    f32x4v y0 = MFMA16(cfr[t], pvf[0], ((f32x4v){0.f,0.f,0.f,0.f}));
    f32x4v y1 = MFMA16(cfr[t], pvf[1], ((f32x4v){0.f,0.f,0.f,0.f}));
    #pragma unroll
    for (int r = 0; r < 4; ++r) { y0[r] *= el[r]; y1[r] *= el[r]; }

    #pragma unroll
    for (int kp = 0; kp < 8; ++kp) {
      if (2 * kp <= LT) {
        f32x4v s0 = MFMA16(cfr[t], bfr[2 * kp],     ((f32x4v){0.f,0.f,0.f,0.f}));
        f32x4v s1 = MFMA16(cfr[t], bfr[2 * kp + 1], ((f32x4v){0.f,0.f,0.f,0.f}));
        const int buf = kp & 1;
        #pragma unroll
        for (int r = 0; r < 4; ++r) {
          int l  = lbase + khalf * 4 + r;
          int sA = 2 * kp * 16 + l16;
          int sB2 = sA + 16;
          float p0 = (sA  <= l) ? s0[r] * __expf(al[r] - sAcum[sA])  : 0.f;
          float p1 = (sB2 <= l) ? s1[r] * __expf(al[r] - sAcum[sB2]) : 0.f;
          sP[wave][buf][khalf * 4 + r][l16]      = (__bf16)p0;
          sP[wave][buf][khalf * 4 + r][16 + l16] = (__bf16)p1;
        }
        bf16x8 pa  = *(const bf16x8*)&sP[wave][buf][l16][khalf * 8];
        bf16x8 xf0 = *(const bf16x8*)&sXT[l16][kp * 32 + khalf * 8];
        bf16x8 xf1 = *(const bf16x8*)&sXT[16 + l16][kp * 32 + khalf * 8];
        y0 = MFMA16(pa, xf0, y0);
        y1 = MFMA16(pa, xf1, y1);
      }
    }

    #pragma unroll
    for (int r = 0; r < 4; ++r) {
      int lg = rowbase + lbase + khalf * 4 + r;
      const float* xr = xconv + (size_t)lg * CONVDIM + h * 32;
      float* yr = y + (size_t)lg * DINNER + h * 32;
      yr[l16]      = y0[r] + Dh * xr[l16];
      yr[16 + l16] = y1[r] + Dh * xr[16 + l16];
    }
  }
}

// ---------------- gate (silu(z)) + RMSNorm -> bf16 ----------------
__global__ __launch_bounds__(256) void gate_norm(const float* __restrict__ y,
    const float* __restrict__ z, const float* __restrict__ norm_w,
    unsigned short* __restrict__ ynbf)
{
  int row = blockIdx.x, t = threadIdx.x;
  const float* yr = y + (size_t)row * DINNER;
  const float* zr = z + (size_t)row * DINNER;
  float vals[8];
  float ss = 0.f;
  #pragma unroll
  for (int i = 0; i < 8; ++i) {
    int ci = t + i * 256;
    float zv = zr[ci];
    float g = zv / (1.f + __expf(-zv));
    float v = yr[ci] * g;
    vals[i] = v; ss += v * v;
  }
  #pragma unroll
  for (int o = 1; o < 64; o <<= 1) ss += __shfl_xor(ss, o);
  __shared__ float sred[4];
  if ((t & 63) == 0) sred[t >> 6] = ss;
  __syncthreads();
  float tot = sred[0] + sred[1] + sred[2] + sred[3];
  float scale = rsqrtf(tot * (1.f / DINNER) + 1e-5f);
  #pragma unroll
  for (int i = 0; i < 8; ++i) {
    int ci = t + i * 256;
    ynbf[(size_t)row * DINNER + ci] = f2bf(vals[i] * scale * norm_w[ci]);
  }
}

// ---------------- launch ----------------
extern "C" void kernel_launch(void* const* d_in, const int* in_sizes, int n_in,
                              void* d_out, int out_size, void* d_ws, size_t ws_size,
                              hipStream_t stream)
{
  const float* u       = (const float*)d_in[0];
  const float* W_in    = (const float*)d_in[1];
  const float* conv_w  = (const float*)d_in[2];
  const float* conv_b  = (const float*)d_in[3];
  const float* dt_bias = (const float*)d_in[4];
  const float* A_log   = (const float*)d_in[5];
  const float* Dv      = (const float*)d_in[6];
  const float* norm_w  = (const float*)d_in[7];
  const float* W_out   = (const float*)d_in[8];

  float* out  = (float*)d_out;
  float* zout = out + (size_t)BL * DMODEL;

  char* ws = (char*)d_ws;
  size_t off = 0;
  auto alloc = [&](size_t bytes){ size_t o = off; off += (bytes + 255) & ~(size_t)255; return o; };
  size_t o_ubf    = alloc((size_t)BL * DMODEL * 2);
  size_t o_wbf    = alloc((size_t)NPAD * DMODEL * 2);
  size_t o_xbcdt  = alloc((size_t)BL * XWIDTH * 4);
  size_t o_xconv  = alloc((size_t)BL * CONVDIM * 4);
  size_t o_dt     = alloc((size_t)BL * NHEADS * 4);
  size_t o_acum   = alloc((size_t)1024 * 256 * 4);
  size_t o_decay  = alloc((size_t)1024 * 4);
  size_t o_states = alloc((size_t)1024 * 512 * 4);
  size_t o_prev   = alloc((size_t)1024 * 512 * 4);
  size_t o_ynbf   = alloc((size_t)BL * DINNER * 2);

  unsigned short* ubf    = (unsigned short*)(ws + o_ubf);
  unsigned short* wbf    = (unsigned short*)(ws + o_wbf);
  float*          xbcdt  = (float*)(ws + o_xbcdt);
  float*          xconv  = (float*)(ws + o_xconv);
  float*          dtws   = (float*)(ws + o_dt);
  float*          acum   = (float*)(ws + o_acum);
  float*          decay  = (float*)(ws + o_decay);
  float*          states = (float*)(ws + o_states);
  float*          prevb  = (float*)(ws + o_prev);
  unsigned short* ynbf   = (unsigned short*)(ws + o_ynbf);
  unsigned short* woutbf = ubf;
  float*          ywork  = xbcdt;

  cast_f32_bf16<<<(BL * DMODEL) / 256, 256, 0, stream>>>(u, ubf, BL * DMODEL);
  cast_win_pad<<<(NPAD * DMODEL) / 256, 256, 0, stream>>>(W_in, wbf);

  gemm_bf16<0><<<dim3(NPAD / 128, BL / 128), 256, 0, stream>>>(ubf, wbf, DMODEL, zout, xbcdt, 0);

  conv_dt_kernel<<<(BL * XWIDTH) / 256, 256, 0, stream>>>(xbcdt, conv_w, conv_b, dt_bias, xconv, dtws);

  ssd_phaseA<<<dim3(16, 64), 256, 0, stream>>>(xconv, dtws, A_log, acum, decay, states);
  ssd_phaseB<<<128, 512, 0, stream>>>(states, decay, prevb);
  ssd_phaseC_mfma<<<dim3(16, 64), 256, 0, stream>>>(xconv, dtws, acum, prevb, Dv, ywork);

  gate_norm<<<BL, 256, 0, stream>>>(ywork, zout, norm_w, ynbf);

  cast_f32_bf16<<<(DMODEL * DINNER) / 256, 256, 0, stream>>>(W_out, woutbf, DMODEL * DINNER);

  gemm_bf16<1><<<dim3(DMODEL / 128, BL / 128), 256, 0, stream>>>(ynbf, woutbf, DINNER, out, nullptr, DMODEL);
}

// Round 4
// 246.289 us; speedup vs baseline: 1.5693x; 1.0410x over previous
//
#include <hip/hip_runtime.h>

#define BATCH   2
#define SEQLEN  2048
#define DMODEL  1024
#define DINNER  2048
#define NHEADS  64
#define HEADDIM 32
#define DSTATE  16
#define CONVDIM 2080
#define DINPROJ 4192
#define NPAD    4224
#define CHUNK   256
#define NCHUNK  8
#define BL      (BATCH*SEQLEN)   // 4096
#define XWIDTH  2144             // CONVDIM + NHEADS

typedef float  f4    __attribute__((ext_vector_type(4)));
typedef short  s16x8 __attribute__((ext_vector_type(8)));
typedef __bf16 bf16x8 __attribute__((ext_vector_type(8)));
typedef float  f32x4v __attribute__((ext_vector_type(4)));

#define MFMA16(a,b,c) __builtin_amdgcn_mfma_f32_16x16x32_bf16((a),(b),(c),0,0,0)

__device__ __forceinline__ unsigned short f2bf(float f){
  unsigned int u = __float_as_uint(f);
  u += 0x7FFFu + ((u >> 16) & 1u);
  return (unsigned short)(u >> 16);
}

__device__ __forceinline__ void gload_lds16(const void* g, void* l){
  __builtin_amdgcn_global_load_lds((const __attribute__((address_space(1))) unsigned int*)g,
                                   (__attribute__((address_space(3))) unsigned int*)l,
                                   16, 0, 0);
}

// load 8 consecutive f32 -> bf16x8 fragment; if !valid, return zeros.
__device__ __forceinline__ bf16x8 f32x8_to_frag(const float* src, bool valid){
  bf16x8 r;
  if (valid) {
    f4 a = *(const f4*)src;
    f4 c = *(const f4*)(src + 4);
    r[0]=(__bf16)a[0]; r[1]=(__bf16)a[1]; r[2]=(__bf16)a[2]; r[3]=(__bf16)a[3];
    r[4]=(__bf16)c[0]; r[5]=(__bf16)c[1]; r[6]=(__bf16)c[2]; r[7]=(__bf16)c[3];
  } else {
    r[0]=(__bf16)0.f; r[1]=(__bf16)0.f; r[2]=(__bf16)0.f; r[3]=(__bf16)0.f;
    r[4]=(__bf16)0.f; r[5]=(__bf16)0.f; r[6]=(__bf16)0.f; r[7]=(__bf16)0.f;
  }
  return r;
}

// ---------------- casts ----------------
__global__ void cast_f32_bf16(const float* __restrict__ in, unsigned short* __restrict__ out, int n){
  int i = blockIdx.x * 256 + threadIdx.x;
  if (i < n) out[i] = f2bf(in[i]);
}

__global__ void cast_win_pad(const float* __restrict__ in, unsigned short* __restrict__ out){
  int i = blockIdx.x * 256 + threadIdx.x;
  if (i >= NPAD * DMODEL) return;
  int r = i >> 10;  // /1024
  out[i] = (r < DINPROJ) ? f2bf(in[i]) : (unsigned short)0;
}

// ---------------- bf16 MFMA GEMM: C[M,N] = A[M,K] * B[N,K]^T ----------------
// 2-phase double-buffered global_load_lds staging + chunk-XOR LDS swizzle +
// XCD-bijective block swizzle.
// MODE 0: in_proj epilogue split (z / xbcdt); MODE 1: plain store ld N.
template<int MODE>
__global__ __launch_bounds__(256) void gemm_bf16(
    const unsigned short* __restrict__ A,
    const unsigned short* __restrict__ B,
    int K, float* __restrict__ C0, float* __restrict__ C1, int N)
{
  __shared__ unsigned short As[2][128][32];
  __shared__ unsigned short Bs[2][128][32];

  // XCD-bijective swizzle (nwg divisible by 8 for both our grids)
  const int nx   = gridDim.x;
  const int flat = blockIdx.y * nx + blockIdx.x;
  const int q    = (nx * gridDim.y) >> 3;
  const int swz  = (flat & 7) * q + (flat >> 3);
  const int bm   = swz / nx, bn = swz % nx;

  const int tid  = threadIdx.x;
  const int wave = tid >> 6, lane = tid & 63;
  const int wm   = (wave >> 1) * 64, wn = (wave & 1) * 64;
  const int lrow = lane & 15, khalf = lane >> 4;
  const int cswz = (khalf ^ (lrow & 3)) * 8;   // swizzled chunk offset for ds_read

  // staging: lane -> LDS row wave*16 + (lane>>2), chunk lane&3 (linear dest).
  // global source chunk pre-XOR'd with row&3 so LDS holds swizzled layout.
  const int srow = wave * 16 + (lane >> 2);
  const int scol = (((lane & 3) ^ ((lane >> 2) & 3))) * 8;
  const unsigned short* Ag = A + (size_t)(bm * 128 + srow) * K + scol;
  const unsigned short* Bg = B + (size_t)(bn * 128 + srow) * K + scol;
  const int lr0 = wave * 16;

  f32x4v acc[4][4];
  #pragma unroll
  for (int i = 0; i < 4; ++i)
    #pragma unroll
    for (int j = 0; j < 4; ++j)
      acc[i][j] = (f32x4v){0.f,0.f,0.f,0.f};

  auto stage = [&](int buf, int k0){
    gload_lds16(Ag + k0,                   &As[buf][lr0][0]);
    gload_lds16(Ag + k0 + (size_t)64 * K,  &As[buf][64 + lr0][0]);
    gload_lds16(Bg + k0,                   &Bs[buf][lr0][0]);
    gload_lds16(Bg + k0 + (size_t)64 * K,  &Bs[buf][64 + lr0][0]);
  };

  const int NT = K >> 5;
  stage(0, 0);
  __syncthreads();
  for (int t = 0; t < NT; ++t) {
    const int cur = t & 1;
    if (t + 1 < NT) stage(cur ^ 1, (t + 1) << 5);
    bf16x8 af[4], bfr[4];
    #pragma unroll
    for (int i = 0; i < 4; ++i) {
      af[i]  = *(const bf16x8*)&As[cur][wm + i * 16 + lrow][cswz];
      bfr[i] = *(const bf16x8*)&Bs[cur][wn + i * 16 + lrow][cswz];
    }
    #pragma unroll
    for (int mi = 0; mi < 4; ++mi)
      #pragma unroll
      for (int ni = 0; ni < 4; ++ni)
        acc[mi][ni] = MFMA16(af[mi], bfr[ni], acc[mi][ni]);
    if (t + 1 < NT) __syncthreads();
  }

  const int orow0 = bm * 128 + wm;
  const int ocol0 = bn * 128 + wn;
  #pragma unroll
  for (int mi = 0; mi < 4; ++mi)
    #pragma unroll
    for (int ni = 0; ni < 4; ++ni) {
      int col  = ocol0 + ni * 16 + (lane & 15);
      int rowb = orow0 + mi * 16 + (lane >> 4) * 4;
      #pragma unroll
      for (int r = 0; r < 4; ++r) {
        int row = rowb + r;
        float v = acc[mi][ni][r];
        if (MODE == 0) {
          if (col < DINNER)        C0[(size_t)row * DINNER + col] = v;
          else if (col < DINPROJ)  C1[(size_t)row * XWIDTH + (col - DINNER)] = v;
        } else {
          C0[(size_t)row * N + col] = v;
        }
      }
    }
}

// ---------------- conv1d (depthwise causal, silu) + dt softplus ----------------
__global__ void conv_dt_kernel(const float* __restrict__ xbcdt,
                               const float* __restrict__ conv_w, const float* __restrict__ conv_b,
                               const float* __restrict__ dt_bias,
                               float* __restrict__ xconv, float* __restrict__ dtout)
{
  int idx = blockIdx.x * 256 + threadIdx.x;
  if (idx >= BL * XWIDTH) return;
  int ch = idx % XWIDTH;
  int bl = idx / XWIDTH;
  int l  = bl & (SEQLEN - 1);
  if (ch < CONVDIM) {
    float acc = conv_b[ch];
    #pragma unroll
    for (int j = 0; j < 4; ++j) {
      int ls = l - 3 + j;
      float x = (ls >= 0) ? xbcdt[(size_t)(bl - 3 + j) * XWIDTH + ch] : 0.f;
      acc += conv_w[ch * 4 + j] * x;
    }
    float s = acc / (1.f + __expf(-acc));
    xconv[(size_t)bl * CONVDIM + ch] = s;
  } else {
    int h = ch - CONVDIM;
    float x = xbcdt[(size_t)bl * XWIDTH + ch] + dt_bias[h];
    float dtv = (x > 20.f) ? x : log1pf(__expf(x));
    dtout[bl * NHEADS + h] = dtv;
  }
}

// ---------------- SSD phase A: Acum scan + chunk states ----------------
__global__ __launch_bounds__(256) void ssd_phaseA(
    const float* __restrict__ xconv, const float* __restrict__ dt,
    const float* __restrict__ A_log,
    float* __restrict__ acum, float* __restrict__ decay, float* __restrict__ states)
{
  int bc = blockIdx.x, h = blockIdx.y;
  int b = bc >> 3;
  int t = threadIdx.x;
  __shared__ float sAc[256], sCoef[256], sDt[256];
  __shared__ float sB[256][16];
  __shared__ float sX[256][32];
  int rowbase = b * SEQLEN + (bc & 7) * CHUNK;
  float dtv = dt[(rowbase + t) * NHEADS + h];
  float Av  = -__expf(A_log[h]);
  sAc[t] = dtv * Av; sDt[t] = dtv;
  for (int i = t; i < 256 * 16; i += 256) { int l = i >> 4, n = i & 15; sB[l][n] = xconv[(size_t)(rowbase + l) * CONVDIM + DINNER + n]; }
  for (int i = t; i < 256 * 32; i += 256) { int l = i >> 5, p = i & 31; sX[l][p] = xconv[(size_t)(rowbase + l) * CONVDIM + h * 32 + p]; }
  __syncthreads();
  for (int off = 1; off < 256; off <<= 1) {
    float add = (t >= off) ? sAc[t - off] : 0.f;
    __syncthreads();
    sAc[t] += add;
    __syncthreads();
  }
  int bch = bc * 64 + h;
  acum[(size_t)bch * 256 + t] = sAc[t];
  float last = sAc[255];
  if (t == 0) decay[bch] = __expf(last);
  sCoef[t] = sDt[t] * __expf(last - sAc[t]);
  __syncthreads();
  #pragma unroll
  for (int o = 0; o < 2; ++o) {
    int oi = t + o * 256;
    int p = oi >> 4, n = oi & 15;
    float acc = 0.f;
    for (int l = 0; l < 256; ++l) acc += sCoef[l] * sB[l][n] * sX[l][p];
    states[(size_t)bch * 512 + oi] = acc;
  }
}

// ---------------- SSD phase B: sequential chunk scan ----------------
__global__ void ssd_phaseB(const float* __restrict__ states, const float* __restrict__ decay,
                           float* __restrict__ prev)
{
  int bh = blockIdx.x;           // b*64+h, 128 blocks
  int b = bh >> 6, h = bh & 63;
  int t = threadIdx.x;           // 512
  float carry = 0.f;
  for (int c = 0; c < NCHUNK; ++c) {
    int bch = (b * 8 + c) * 64 + h;
    size_t base = (size_t)bch * 512 + t;
    prev[base] = carry;
    carry = decay[bch] * carry + states[base];
  }
}

// ---------------- SSD phase C (MFMA): Y = (CB^T ∘ L)·xdt + e^{acum}·C·prev^T + D·x ----
__global__ __launch_bounds__(256, 2) void ssd_phaseC_mfma(
    const float* __restrict__ xconv, const float* __restrict__ dt,
    const float* __restrict__ acum, const float* __restrict__ prev,
    const float* __restrict__ Dvec, float* __restrict__ y)
{
  const int bc = blockIdx.x, h = blockIdx.y;
  const int b = bc >> 3;
  const int rowbase = b * SEQLEN + (bc & 7) * CHUNK;
  const int bch = bc * 64 + h;
  const int tid = threadIdx.x, wave = tid >> 6, lane = tid & 63;
  const int l16 = lane & 15, khalf = lane >> 4;

  __shared__ float sAcum[256];
  __shared__ __bf16 sXT[32][264];          // [p][s] = x[s][p]*dt[s]
  __shared__ __bf16 sP[4][2][16][40];      // per-wave double-buffered P slab

  if (tid < 256) sAcum[tid] = acum[(size_t)bch * 256 + tid];
  {
    int l  = tid >> 3;
    int p0 = (tid & 7) * 4;
    #pragma unroll
    for (int pass = 0; pass < 8; ++pass) {
      int ls = l + pass * 32;
      const float* xr = xconv + (size_t)(rowbase + ls) * CONVDIM + h * 32 + p0;
      f4 v = *(const f4*)xr;
      float dtl = dt[(rowbase + ls) * NHEADS + h];
      #pragma unroll
      for (int j = 0; j < 4; ++j) sXT[p0 + j][ls] = (__bf16)(v[j] * dtl);
    }
  }

  // register fragments (upper-K halves zeroed so B-pad can't leak)
  const bool kv = (khalf < 2);
  bf16x8 bfr[16], cfr[4], pvf[2];
  #pragma unroll
  for (int i = 0; i < 16; ++i)
    bfr[i] = f32x8_to_frag(xconv + (size_t)(rowbase + i * 16 + l16) * CONVDIM + DINNER + khalf * 8, kv);
  #pragma unroll
  for (int t = 0; t < 4; ++t)
    cfr[t] = f32x8_to_frag(xconv + (size_t)(rowbase + (wave + 4 * t) * 16 + l16) * CONVDIM + DINNER + DSTATE + khalf * 8, kv);
  #pragma unroll
  for (int pt = 0; pt < 2; ++pt)
    pvf[pt] = f32x8_to_frag(prev + (size_t)bch * 512 + (pt * 16 + l16) * 16 + khalf * 8, kv);
  __syncthreads();

  const float Dh = Dvec[h];
  #pragma unroll
  for (int t = 0; t < 4; ++t) {
    const int LT = wave + 4 * t;
    const int lbase = LT * 16;
    float al[4], el[4];
    #pragma unroll
    for (int r = 0; r < 4; ++r) { al[r] = sAcum[lbase + khalf * 4 + r]; el[r] = __expf(al[r]); }
    f32x4v y0 = MFMA16(cfr[t], pvf[0], ((f32x4v){0.f,0.f,0.f,0.f}));
    f32x4v y1 = MFMA16(cfr[t], pvf[1], ((f32x4v){0.f,0.f,0.f,0.f}));
    #pragma unroll
    for (int r = 0; r < 4; ++r) { y0[r] *= el[r]; y1[r] *= el[r]; }

    #pragma unroll
    for (int kp = 0; kp < 8; ++kp) {
      if (2 * kp <= LT) {
        f32x4v s0 = MFMA16(cfr[t], bfr[2 * kp],     ((f32x4v){0.f,0.f,0.f,0.f}));
        f32x4v s1 = MFMA16(cfr[t], bfr[2 * kp + 1], ((f32x4v){0.f,0.f,0.f,0.f}));
        const int buf = kp & 1;
        #pragma unroll
        for (int r = 0; r < 4; ++r) {
          int l  = lbase + khalf * 4 + r;
          int sA = 2 * kp * 16 + l16;
          int sB2 = sA + 16;
          float p0 = (sA  <= l) ? s0[r] * __expf(al[r] - sAcum[sA])  : 0.f;
          float p1 = (sB2 <= l) ? s1[r] * __expf(al[r] - sAcum[sB2]) : 0.f;
          sP[wave][buf][khalf * 4 + r][l16]      = (__bf16)p0;
          sP[wave][buf][khalf * 4 + r][16 + l16] = (__bf16)p1;
        }
        bf16x8 pa  = *(const bf16x8*)&sP[wave][buf][l16][khalf * 8];
        bf16x8 xf0 = *(const bf16x8*)&sXT[l16][kp * 32 + khalf * 8];
        bf16x8 xf1 = *(const bf16x8*)&sXT[16 + l16][kp * 32 + khalf * 8];
        y0 = MFMA16(pa, xf0, y0);
        y1 = MFMA16(pa, xf1, y1);
      }
    }

    #pragma unroll
    for (int r = 0; r < 4; ++r) {
      int lg = rowbase + lbase + khalf * 4 + r;
      const float* xr = xconv + (size_t)lg * CONVDIM + h * 32;
      float* yr = y + (size_t)lg * DINNER + h * 32;
      yr[l16]      = y0[r] + Dh * xr[l16];
      yr[16 + l16] = y1[r] + Dh * xr[16 + l16];
    }
  }
}

// ---------------- gate (silu(z)) + RMSNorm -> bf16 ----------------
__global__ __launch_bounds__(256) void gate_norm(const float* __restrict__ y,
    const float* __restrict__ z, const float* __restrict__ norm_w,
    unsigned short* __restrict__ ynbf)
{
  int row = blockIdx.x, t = threadIdx.x;
  const float* yr = y + (size_t)row * DINNER;
  const float* zr = z + (size_t)row * DINNER;
  float vals[8];
  float ss = 0.f;
  #pragma unroll
  for (int i = 0; i < 8; ++i) {
    int ci = t + i * 256;
    float zv = zr[ci];
    float g = zv / (1.f + __expf(-zv));
    float v = yr[ci] * g;
    vals[i] = v; ss += v * v;
  }
  #pragma unroll
  for (int o = 1; o < 64; o <<= 1) ss += __shfl_xor(ss, o);
  __shared__ float sred[4];
  if ((t & 63) == 0) sred[t >> 6] = ss;
  __syncthreads();
  float tot = sred[0] + sred[1] + sred[2] + sred[3];
  float scale = rsqrtf(tot * (1.f / DINNER) + 1e-5f);
  #pragma unroll
  for (int i = 0; i < 8; ++i) {
    int ci = t + i * 256;
    ynbf[(size_t)row * DINNER + ci] = f2bf(vals[i] * scale * norm_w[ci]);
  }
}

// ---------------- launch ----------------
extern "C" void kernel_launch(void* const* d_in, const int* in_sizes, int n_in,
                              void* d_out, int out_size, void* d_ws, size_t ws_size,
                              hipStream_t stream)
{
  const float* u       = (const float*)d_in[0];
  const float* W_in    = (const float*)d_in[1];
  const float* conv_w  = (const float*)d_in[2];
  const float* conv_b  = (const float*)d_in[3];
  const float* dt_bias = (const float*)d_in[4];
  const float* A_log   = (const float*)d_in[5];
  const float* Dv      = (const float*)d_in[6];
  const float* norm_w  = (const float*)d_in[7];
  const float* W_out   = (const float*)d_in[8];

  float* out  = (float*)d_out;
  float* zout = out + (size_t)BL * DMODEL;

  char* ws = (char*)d_ws;
  size_t off = 0;
  auto alloc = [&](size_t bytes){ size_t o = off; off += (bytes + 255) & ~(size_t)255; return o; };
  size_t o_ubf    = alloc((size_t)BL * DMODEL * 2);
  size_t o_wbf    = alloc((size_t)NPAD * DMODEL * 2);
  size_t o_xbcdt  = alloc((size_t)BL * XWIDTH * 4);
  size_t o_xconv  = alloc((size_t)BL * CONVDIM * 4);
  size_t o_dt     = alloc((size_t)BL * NHEADS * 4);
  size_t o_acum   = alloc((size_t)1024 * 256 * 4);
  size_t o_decay  = alloc((size_t)1024 * 4);
  size_t o_states = alloc((size_t)1024 * 512 * 4);
  size_t o_prev   = alloc((size_t)1024 * 512 * 4);
  size_t o_ynbf   = alloc((size_t)BL * DINNER * 2);

  unsigned short* ubf    = (unsigned short*)(ws + o_ubf);
  unsigned short* wbf    = (unsigned short*)(ws + o_wbf);
  float*          xbcdt  = (float*)(ws + o_xbcdt);
  float*          xconv  = (float*)(ws + o_xconv);
  float*          dtws   = (float*)(ws + o_dt);
  float*          acum   = (float*)(ws + o_acum);
  float*          decay  = (float*)(ws + o_decay);
  float*          states = (float*)(ws + o_states);
  float*          prevb  = (float*)(ws + o_prev);
  unsigned short* ynbf   = (unsigned short*)(ws + o_ynbf);
  unsigned short* woutbf = ubf;
  float*          ywork  = xbcdt;

  cast_f32_bf16<<<(BL * DMODEL) / 256, 256, 0, stream>>>(u, ubf, BL * DMODEL);
  cast_win_pad<<<(NPAD * DMODEL) / 256, 256, 0, stream>>>(W_in, wbf);

  gemm_bf16<0><<<dim3(NPAD / 128, BL / 128), 256, 0, stream>>>(ubf, wbf, DMODEL, zout, xbcdt, 0);

  conv_dt_kernel<<<(BL * XWIDTH) / 256, 256, 0, stream>>>(xbcdt, conv_w, conv_b, dt_bias, xconv, dtws);

  ssd_phaseA<<<dim3(16, 64), 256, 0, stream>>>(xconv, dtws, A_log, acum, decay, states);
  ssd_phaseB<<<128, 512, 0, stream>>>(states, decay, prevb);
  ssd_phaseC_mfma<<<dim3(16, 64), 256, 0, stream>>>(xconv, dtws, acum, prevb, Dv, ywork);

  gate_norm<<<BL, 256, 0, stream>>>(ywork, zout, norm_w, ynbf);

  cast_f32_bf16<<<(DMODEL * DINNER) / 256, 256, 0, stream>>>(W_out, woutbf, DMODEL * DINNER);

  gemm_bf16<1><<<dim3(DMODEL / 128, BL / 128), 256, 0, stream>>>(ynbf, woutbf, DINNER, out, nullptr, DMODEL);
}